// Round 1
// baseline (3911.386 us; speedup 1.0000x reference)
//
#include <hip/hip_runtime.h>

// ---------------------------------------------------------------------------
// MDGRU fused implementation, MI355X (gfx950)
//   B=64, T=2048, D=256, U=256, 3U=768
//   Kernel 1: proj[b][t][0:768] = X[b][t][:] @ kernel + bias   (f16 in d_ws)
//   Kernel 2: per-batch persistent GRU scan, weights in VGPRs, state in LDS
// ---------------------------------------------------------------------------

typedef _Float16 half2_t __attribute__((ext_vector_type(2)));
typedef _Float16 half8_t __attribute__((ext_vector_type(8)));
typedef float    float4_t __attribute__((ext_vector_type(4)));

#define T_LEN 2048
#define B_SZ  64
#define D_IN  256
#define N3    768   // 3*U
#define U_SZ  256

// extract half2 p (p=0..3) from a half8
#define H2(v, p) __builtin_shufflevector((v), (v), 2*(p), 2*(p)+1)

__device__ __forceinline__ float fdot2f(half2_t a, half2_t b, float c) {
#if __has_builtin(__builtin_amdgcn_fdot2)
    return __builtin_amdgcn_fdot2(a, b, c, false);
#else
    // compiler lowers to v_fma_mix_f32 pairs
    return c + (float)a[0]*(float)b[0] + (float)a[1]*(float)b[1];
#endif
}

__device__ __forceinline__ float fast_sigmoid(float s) {
    // 1/(1+2^(-s*log2 e)); saturates cleanly at +/-inf
    return __builtin_amdgcn_rcpf(1.0f + __builtin_amdgcn_exp2f(-1.44269504f * s));
}
__device__ __forceinline__ float fast_tanh(float s) {
    // tanh(s) = 1 - 2/(1+e^(2s)) ; e^(2s) = 2^(2.885390*s)
    return 1.0f - 2.0f * __builtin_amdgcn_rcpf(1.0f + __builtin_amdgcn_exp2f(2.88539008f * s));
}

// ---------------------------------------------------------------------------
// Kernel 1: proj GEMM.  Tile: 64 rows (M) x 48 cols (N), K=256 staged once.
// GA_LD=264 f16 (=528 B, multiple of 16 B) keeps b128 reads aligned and
// row-stride == 4 banks mod 32 -> <=2-way conflicts on the read patterns.
// ---------------------------------------------------------------------------
#define GA_LD 264
#define NT_N  16          // 768/48
#define MT_M  2048        // 131072/64

__global__ __launch_bounds__(256) void proj_gemm(
    const float* __restrict__ X, const float* __restrict__ W,
    const float* __restrict__ bias, _Float16* __restrict__ proj)
{
    __shared__ __align__(16) _Float16 Ah[64 * GA_LD];   // [row][k]
    __shared__ __align__(16) _Float16 Wh[48 * GA_LD];   // [col][k]

    // XCD-cluster swizzle: keep the 16 blocks sharing one A-panel on one XCD
    // (dispatch round-robins bid%8 -> XCD). bij: bid <-> (mt,nt).
    unsigned bid = blockIdx.x;
    unsigned idx = bid >> 3;                       // 0..4095
    unsigned mt  = (bid & 7) * (MT_M / 8) + (idx >> 4);
    unsigned nt  = idx & (NT_N - 1);
    int m0 = mt * 64, n0 = nt * 48;
    int tid = threadIdx.x;

    // ---- stage A (64x256 fp32 -> f16), coalesced float4 reads
    {
        int r = tid >> 6;            // 0..3
        int k = (tid & 63) * 4;      // 0..252
        #pragma unroll
        for (int i = 0; i < 16; ++i) {
            int row = i * 4 + r;
            float4_t v = *(const float4_t*)(X + (size_t)(m0 + row) * D_IN + k);
            _Float16* p = Ah + row * GA_LD + k;
            p[0] = (_Float16)v.x; p[1] = (_Float16)v.y;
            p[2] = (_Float16)v.z; p[3] = (_Float16)v.w;
        }
    }
    // ---- stage W transposed: read W[k][n0+c] coalesced, write Wh[c][k]
    {
        int c  = tid & 63;           // 0..63, active if <48
        int kk = tid >> 6;           // 0..3
        if (c < 48) {
            #pragma unroll 4
            for (int i = 0; i < 64; ++i) {
                int krow = i * 4 + kk;
                Wh[c * GA_LD + krow] = (_Float16)W[(size_t)krow * N3 + n0 + c];
            }
        }
    }
    __syncthreads();

    int r0 = (tid >> 4) << 2;        // rows r0..r0+3
    int c  = tid & 15;               // cols c, c+16, c+32
    float acc[4][3];
    #pragma unroll
    for (int rr = 0; rr < 4; ++rr)
        #pragma unroll
        for (int cc = 0; cc < 3; ++cc) acc[rr][cc] = 0.0f;

    for (int j = 0; j < 32; ++j) {   // 8-k chunks
        half8_t av[4], wv[3];
        #pragma unroll
        for (int rr = 0; rr < 4; ++rr)
            av[rr] = *(const half8_t*)(Ah + (r0 + rr) * GA_LD + j * 8);
        #pragma unroll
        for (int cc = 0; cc < 3; ++cc)
            wv[cc] = *(const half8_t*)(Wh + (c + 16 * cc) * GA_LD + j * 8);
        #pragma unroll
        for (int rr = 0; rr < 4; ++rr)
            #pragma unroll
            for (int cc = 0; cc < 3; ++cc) {
                acc[rr][cc] = fdot2f(H2(av[rr],0), H2(wv[cc],0), acc[rr][cc]);
                acc[rr][cc] = fdot2f(H2(av[rr],1), H2(wv[cc],1), acc[rr][cc]);
                acc[rr][cc] = fdot2f(H2(av[rr],2), H2(wv[cc],2), acc[rr][cc]);
                acc[rr][cc] = fdot2f(H2(av[rr],3), H2(wv[cc],3), acc[rr][cc]);
            }
    }

    float bv[3];
    #pragma unroll
    for (int cc = 0; cc < 3; ++cc) bv[cc] = bias[n0 + c + 16 * cc];
    #pragma unroll
    for (int rr = 0; rr < 4; ++rr)
        #pragma unroll
        for (int cc = 0; cc < 3; ++cc)
            proj[(size_t)(m0 + r0 + rr) * N3 + (n0 + c + 16 * cc)] =
                (_Float16)(acc[rr][cc] + bv[cc]);
}

// ---------------------------------------------------------------------------
// Kernel 2: persistent GRU scan. 64 blocks (one per batch) x 768 threads.
// thread (g = tid/256, u = tid%256) owns weight column RK[:, g*256+u]
// as 128 half2 VGPRs (fully unrolled -> static register indexing).
// State: aF (fp32, authoritative) + aH (f16 mirror for dot products).
// Phase 1 (g<2): z,r = sigmoid(a@U + x);  r-thread writes ra = r*a (f16).
// Phase 2 (g==2): h = tanh(ra@Uh + x); a' = z*a + (1-z)*h.
// Branch granularity is whole waves (g boundaries at tid 256/512).
// ---------------------------------------------------------------------------
__global__ __launch_bounds__(768) void gru_scan(
    const float* __restrict__ RK, const _Float16* __restrict__ proj,
    float* __restrict__ out)
{
    __shared__ __align__(16) _Float16 aH[U_SZ];    // f16 mirror of state
    __shared__ __align__(16) _Float16 raH[U_SZ];   // f16 r*a
    __shared__ float zS[U_SZ];
    __shared__ float aF[U_SZ];                     // fp32 state (authoritative)

    const int b   = blockIdx.x;
    const int tid = threadIdx.x;
    const int g   = tid >> 8;       // 0=z, 1=r, 2=h
    const int u   = tid & 255;

    // ---- load this thread's weight column, fp32 -> packed half2 in VGPRs
    half2_t wcol[128];
    {
        const float* wp = RK + (size_t)(g << 8) + u;   // RK[k][g*256+u], stride 768
        #pragma unroll
        for (int k2 = 0; k2 < 128; ++k2) {
            half2_t h;
            h[0] = (_Float16)wp[(size_t)(2 * k2)     * N3];
            h[1] = (_Float16)wp[(size_t)(2 * k2 + 1) * N3];
            wcol[k2] = h;
        }
    }

    if (tid < U_SZ) { aF[tid] = 0.0f; aH[tid] = (_Float16)0.0f; }

    // x stream for this thread: proj[b][t][g*256+u]
    const _Float16* px = proj + ((size_t)b * T_LEN) * N3 + (g << 8) + u;
    float xv = (float)px[0];                        // prefetch t=0
    __syncthreads();

    for (int t = 0; t < T_LEN; ++t) {
        const float x_cur = xv;
        if (t + 1 < T_LEN) xv = (float)px[(size_t)(t + 1) * N3];  // prefetch

        if (g < 2) {
            // ---- phase 1: a @ U{z,r}  (broadcast reads of aH)
            float acc = 0.0f;
            #pragma unroll
            for (int j = 0; j < 32; ++j) {
                half8_t av = *(const half8_t*)(aH + j * 8);
                acc = fdot2f(H2(av,0), wcol[4*j+0], acc);
                acc = fdot2f(H2(av,1), wcol[4*j+1], acc);
                acc = fdot2f(H2(av,2), wcol[4*j+2], acc);
                acc = fdot2f(H2(av,3), wcol[4*j+3], acc);
            }
            float sig = fast_sigmoid(acc + x_cur);
            if (g == 0) zS[u]  = sig;
            else        raH[u] = (_Float16)(sig * aF[u]);   // r * a
        }
        __syncthreads();

        if (g == 2) {
            // ---- phase 2: (r*a) @ Uh, gate update
            float acc = 0.0f;
            #pragma unroll
            for (int j = 0; j < 32; ++j) {
                half8_t rv = *(const half8_t*)(raH + j * 8);
                acc = fdot2f(H2(rv,0), wcol[4*j+0], acc);
                acc = fdot2f(H2(rv,1), wcol[4*j+1], acc);
                acc = fdot2f(H2(rv,2), wcol[4*j+2], acc);
                acc = fdot2f(H2(rv,3), wcol[4*j+3], acc);
            }
            float h  = fast_tanh(acc + x_cur);
            float z  = zS[u];
            float an = z * aF[u] + (1.0f - z) * h;
            aF[u] = an;
            aH[u] = (_Float16)an;
        }
        __syncthreads();
    }

    if (g == 0) out[(size_t)b * U_SZ + u] = aF[u];
}

// ---------------------------------------------------------------------------
extern "C" void kernel_launch(void* const* d_in, const int* in_sizes, int n_in,
                              void* d_out, int out_size, void* d_ws, size_t ws_size,
                              hipStream_t stream)
{
    const float* X    = (const float*)d_in[0];   // (64,2048,256)
    const float* W    = (const float*)d_in[1];   // (256,768)
    const float* RK   = (const float*)d_in[2];   // (256,768)
    const float* bias = (const float*)d_in[3];   // (768,)
    _Float16* proj = (_Float16*)d_ws;            // 131072*768*2 = 201.3 MB

    proj_gemm<<<MT_M * NT_N, 256, 0, stream>>>(X, W, bias, proj);
    gru_scan<<<B_SZ, 768, 0, stream>>>(RK, proj, (float*)d_out);
}

// Round 2
// 3716.639 us; speedup vs baseline: 1.0524x; 1.0524x over previous
//
#include <hip/hip_runtime.h>

// ---------------------------------------------------------------------------
// MDGRU fused implementation, MI355X (gfx950)
//   B=64, T=2048, D=256, U=256, 3U=768
//   Kernel 1: proj[b][t][0:768] = X[b][t][:] @ kernel + bias   (f16 in d_ws)
//   Kernel 2: per-batch persistent GRU scan, ALL weights in VGPRs
//             512 thr/block (8 waves, 2/SIMD) -> 256-VGPR budget/thread.
//             phase1: thread(g,u) owns U{z|r}[:,u]   (128 half2 regs)
//             phase2: thread(hcol,khalf) owns half of Uh[:,hcol] (64 half2)
//                     partials combined via __shfl_xor(1) (in-wave partner)
// ---------------------------------------------------------------------------

typedef _Float16 half2_t __attribute__((ext_vector_type(2)));
typedef _Float16 half8_t __attribute__((ext_vector_type(8)));
typedef float    float4_t __attribute__((ext_vector_type(4)));

#define T_LEN 2048
#define B_SZ  64
#define D_IN  256
#define N3    768   // 3*U
#define U_SZ  256

// extract half2 p (p=0..3) from a half8
#define H2(v, p) __builtin_shufflevector((v), (v), 2*(p), 2*(p)+1)

__device__ __forceinline__ float fdot2f(half2_t a, half2_t b, float c) {
#if __has_builtin(__builtin_amdgcn_fdot2)
    return __builtin_amdgcn_fdot2(a, b, c, false);
#else
    return c + (float)a[0]*(float)b[0] + (float)a[1]*(float)b[1];
#endif
}

__device__ __forceinline__ float fast_sigmoid(float s) {
    return __builtin_amdgcn_rcpf(1.0f + __builtin_amdgcn_exp2f(-1.44269504f * s));
}
__device__ __forceinline__ float fast_tanh(float s) {
    return 1.0f - 2.0f * __builtin_amdgcn_rcpf(1.0f + __builtin_amdgcn_exp2f(2.88539008f * s));
}

// ---------------------------------------------------------------------------
// Kernel 1: proj GEMM (unchanged from passing round-1 version).
// ---------------------------------------------------------------------------
#define GA_LD 264
#define NT_N  16          // 768/48
#define MT_M  2048        // 131072/64

__global__ __launch_bounds__(256) void proj_gemm(
    const float* __restrict__ X, const float* __restrict__ W,
    const float* __restrict__ bias, _Float16* __restrict__ proj)
{
    __shared__ __align__(16) _Float16 Ah[64 * GA_LD];   // [row][k]
    __shared__ __align__(16) _Float16 Wh[48 * GA_LD];   // [col][k]

    unsigned bid = blockIdx.x;
    unsigned idx = bid >> 3;
    unsigned mt  = (bid & 7) * (MT_M / 8) + (idx >> 4);
    unsigned nt  = idx & (NT_N - 1);
    int m0 = mt * 64, n0 = nt * 48;
    int tid = threadIdx.x;

    {
        int r = tid >> 6;
        int k = (tid & 63) * 4;
        #pragma unroll
        for (int i = 0; i < 16; ++i) {
            int row = i * 4 + r;
            float4_t v = *(const float4_t*)(X + (size_t)(m0 + row) * D_IN + k);
            _Float16* p = Ah + row * GA_LD + k;
            p[0] = (_Float16)v.x; p[1] = (_Float16)v.y;
            p[2] = (_Float16)v.z; p[3] = (_Float16)v.w;
        }
    }
    {
        int c  = tid & 63;
        int kk = tid >> 6;
        if (c < 48) {
            #pragma unroll 4
            for (int i = 0; i < 64; ++i) {
                int krow = i * 4 + kk;
                Wh[c * GA_LD + krow] = (_Float16)W[(size_t)krow * N3 + n0 + c];
            }
        }
    }
    __syncthreads();

    int r0 = (tid >> 4) << 2;
    int c  = tid & 15;
    float acc[4][3];
    #pragma unroll
    for (int rr = 0; rr < 4; ++rr)
        #pragma unroll
        for (int cc = 0; cc < 3; ++cc) acc[rr][cc] = 0.0f;

    for (int j = 0; j < 32; ++j) {
        half8_t av[4], wv[3];
        #pragma unroll
        for (int rr = 0; rr < 4; ++rr)
            av[rr] = *(const half8_t*)(Ah + (r0 + rr) * GA_LD + j * 8);
        #pragma unroll
        for (int cc = 0; cc < 3; ++cc)
            wv[cc] = *(const half8_t*)(Wh + (c + 16 * cc) * GA_LD + j * 8);
        #pragma unroll
        for (int rr = 0; rr < 4; ++rr)
            #pragma unroll
            for (int cc = 0; cc < 3; ++cc) {
                acc[rr][cc] = fdot2f(H2(av[rr],0), H2(wv[cc],0), acc[rr][cc]);
                acc[rr][cc] = fdot2f(H2(av[rr],1), H2(wv[cc],1), acc[rr][cc]);
                acc[rr][cc] = fdot2f(H2(av[rr],2), H2(wv[cc],2), acc[rr][cc]);
                acc[rr][cc] = fdot2f(H2(av[rr],3), H2(wv[cc],3), acc[rr][cc]);
            }
    }

    float bv[3];
    #pragma unroll
    for (int cc = 0; cc < 3; ++cc) bv[cc] = bias[n0 + c + 16 * cc];
    #pragma unroll
    for (int rr = 0; rr < 4; ++rr)
        #pragma unroll
        for (int cc = 0; cc < 3; ++cc)
            proj[(size_t)(m0 + r0 + rr) * N3 + (n0 + c + 16 * cc)] =
                (_Float16)(acc[rr][cc] + bv[cc]);
}

// ---------------------------------------------------------------------------
// Kernel 2: persistent GRU scan, 64 blocks x 512 threads.
// ---------------------------------------------------------------------------
__global__ __launch_bounds__(512, 2) void gru_scan(
    const float* __restrict__ RK, const _Float16* __restrict__ proj,
    float* __restrict__ out)
{
    __shared__ __align__(16) _Float16 aH[U_SZ];    // f16 mirror of state
    __shared__ __align__(16) _Float16 raH[U_SZ];   // f16 r*a
    __shared__ float zS[U_SZ];
    __shared__ float aF[U_SZ];                     // fp32 state (authoritative)

    const int b    = blockIdx.x;
    const int tid  = threadIdx.x;
    const int g    = tid >> 8;       // 0=z, 1=r   (wave-uniform: 4 waves each)
    const int u    = tid & 255;
    const int hcol = tid >> 1;       // phase-2 Uh column
    const int kh   = tid & 1;        // phase-2 K-half (0: k<128, 1: k>=128)

    // ---- phase-1 weights: U{z|r}[:,u] as 128 packed half2 VGPRs
    half2_t wA[128];
    {
        const float* wp = RK + (size_t)(g << 8) + u;     // RK[k][g*256+u]
        #pragma unroll
        for (int k2 = 0; k2 < 128; ++k2) {
            half2_t h;
            h[0] = (_Float16)wp[(size_t)(2 * k2)     * N3];
            h[1] = (_Float16)wp[(size_t)(2 * k2 + 1) * N3];
            wA[k2] = h;
        }
    }
    // ---- phase-2 weights: Uh[kh*128 .. +127][hcol] as 64 packed half2 VGPRs
    half2_t wB[64];
    {
        const float* wq = RK + (size_t)(kh * 128) * N3 + 512 + hcol;
        #pragma unroll
        for (int k2 = 0; k2 < 64; ++k2) {
            half2_t h;
            h[0] = (_Float16)wq[(size_t)(2 * k2)     * N3];
            h[1] = (_Float16)wq[(size_t)(2 * k2 + 1) * N3];
            wB[k2] = h;
        }
    }

    if (tid < U_SZ) { aF[tid] = 0.0f; aH[tid] = (_Float16)0.0f; }

    // x streams: phase1 proj[b][t][g*256+u], phase2 proj[b][t][512+hcol]
    const _Float16* px1 = proj + ((size_t)b * T_LEN) * N3 + (g << 8) + u;
    const _Float16* px2 = proj + ((size_t)b * T_LEN) * N3 + 512 + hcol;
    float x1 = (float)px1[0];
    float x2 = (float)px2[0];
    __syncthreads();

    for (int t = 0; t < T_LEN; ++t) {
        const float x1c = x1, x2c = x2;
        if (t + 1 < T_LEN) {
            x1 = (float)px1[(size_t)(t + 1) * N3];
            x2 = (float)px2[(size_t)(t + 1) * N3];
        }

        // ---- phase 1: z,r = sigmoid(a @ U{z,r} + x)   (all 8 waves)
        {
            float a0 = 0.f, a1 = 0.f, a2 = 0.f, a3 = 0.f;
            #pragma unroll
            for (int j = 0; j < 32; ++j) {
                half8_t av = *(const half8_t*)(aH + j * 8);   // broadcast read
                a0 = fdot2f(H2(av,0), wA[4*j+0], a0);
                a1 = fdot2f(H2(av,1), wA[4*j+1], a1);
                a2 = fdot2f(H2(av,2), wA[4*j+2], a2);
                a3 = fdot2f(H2(av,3), wA[4*j+3], a3);
            }
            float sig = fast_sigmoid((a0 + a1) + (a2 + a3) + x1c);
            if (g == 0) zS[u]  = sig;
            else        raH[u] = (_Float16)(sig * aF[u]);     // r * a
        }
        __syncthreads();

        // ---- phase 2: h = tanh((r*a) @ Uh + x); a' = z*a + (1-z)*h
        {
            float b0 = 0.f, b1 = 0.f, b2 = 0.f, b3 = 0.f;
            const _Float16* rbase = raH + (kh << 7);
            #pragma unroll
            for (int j = 0; j < 16; ++j) {
                half8_t rv = *(const half8_t*)(rbase + j * 8); // 2-addr broadcast
                b0 = fdot2f(H2(rv,0), wB[4*j+0], b0);
                b1 = fdot2f(H2(rv,1), wB[4*j+1], b1);
                b2 = fdot2f(H2(rv,2), wB[4*j+2], b2);
                b3 = fdot2f(H2(rv,3), wB[4*j+3], b3);
            }
            float hs = (b0 + b1) + (b2 + b3);
            hs += __shfl_xor(hs, 1, 64);                       // combine K-halves
            if (kh == 0) {
                float h  = fast_tanh(hs + x2c);
                float z  = zS[hcol];
                float an = z * aF[hcol] + (1.0f - z) * h;
                aF[hcol] = an;
                aH[hcol] = (_Float16)an;
            }
        }
        __syncthreads();
    }

    if (tid < U_SZ) out[(size_t)b * U_SZ + tid] = aF[tid];
}

// ---------------------------------------------------------------------------
extern "C" void kernel_launch(void* const* d_in, const int* in_sizes, int n_in,
                              void* d_out, int out_size, void* d_ws, size_t ws_size,
                              hipStream_t stream)
{
    const float* X    = (const float*)d_in[0];   // (64,2048,256)
    const float* W    = (const float*)d_in[1];   // (256,768)
    const float* RK   = (const float*)d_in[2];   // (256,768)
    const float* bias = (const float*)d_in[3];   // (768,)
    _Float16* proj = (_Float16*)d_ws;            // 131072*768*2 = 201.3 MB

    proj_gemm<<<MT_M * NT_N, 256, 0, stream>>>(X, W, bias, proj);
    gru_scan<<<B_SZ, 512, 0, stream>>>(RK, proj, (float*)d_out);
}